// Round 13
// baseline (266.940 us; speedup 1.0000x reference)
//
#include <hip/hip_runtime.h>

// LSTM sliding-window scan. Round-27: BARRIER-FREE COLUMN-OWNED DECOMPOSITION.
// r5-r8 proved the per-step __syncthreads locksteps waves -> MFMA/VALU/trans
// pipes strictly additive; r9-r12 proved 2-blocks/CU co-residency always dies
// on the register allocator. Fix the root cause: each wave owns 32 COLUMNS
// (2 windows x 16 batches) end-to-end -- all 512 gate rows, all 128 h units
// -- so the recurrence is wave-local and the 16-step loop has ZERO barriers.
// GEMM swapped: gates[col][row] = h[col][:] @ W_hh^T[:, row] -> h is the
// MFMA A-operand (read from wave-private LDS h-buf [col][u] as b128 A-frags),
// W_hh^T is the B-operand: kt=0..2 staged once in LDS (96 KiB, shared),
// kt=3 resident in regs (wf3, 128 VGPRs). h written back per ACT as 4
// ds_write_b16 (col-scatter). Block = 4 waves = 128 cols = 8 windows; grid
// 30x8; LDS exactly 128 KiB (harness-proven size); waves_per_eu(1,1) pins
// 1 wave/SIMD -> 512-reg budget (demand ~430, no clamp-spill possible).
// Per wave-step: 8 j-groups x {12 LDS B-frags + 32 MFMA + 8-cell ACT}; the
// j-groups are independent -> ILP overlays MFMA/LDS/trans/VALU in one wave.
// Cell state pre-scaled s = -2*log2e*c (regs, 16 f4v):
//   s' = [s*di*dg + (2log2e*dg - 4log2e)*df] * rcp(di*dg*df)
//   h  = (2-dcc) * rcp(dob*dcc), dcc = 1+exp2(s')  (5 exp2 + 2 rcp / cell)
// Gate scale -log2e (-2log2e for g) folded into bf16 W / f32 wih,bias.
// Layouts (all verified against the session's proven MFMA conventions):
//   A-frag: lane A[m=lm][k=kt*32+lq*8+e]  (m = batch-col within M-tile mt)
//   B-frag: lane B[k=kt*32+lq*8+e][n=lm]  (n = gate-row within tile T=8g+j)
//   D:      lane D[m=4*lq+r][n=lm]        -> cell (col 16mt+4lq+r, u 16j+lm)

#define TT   256
#define WIN  16
#define L2E  1.4426950408889634f

typedef __bf16 bf8 __attribute__((ext_vector_type(8)));
typedef short  s8v __attribute__((ext_vector_type(8)));
typedef float  f4v __attribute__((ext_vector_type(4)));
typedef float  f2v __attribute__((ext_vector_type(2)));

__device__ __forceinline__ unsigned short f2bf(float f) {
    unsigned u = __builtin_bit_cast(unsigned, f);
    return (unsigned short)((u + 0x8000u) >> 16);   // round-half-up to bf16
}
__device__ __forceinline__ float bf2f(short h) {
    return __builtin_bit_cast(float, ((unsigned)(unsigned short)h) << 16);
}
__device__ __forceinline__ int pk_bf16(float a, float b) {
#if __has_builtin(__builtin_amdgcn_cvt_pk_bf16_f32)
    return __builtin_bit_cast(int, __builtin_amdgcn_cvt_pk_bf16_f32(a, b));
#else
    return (int)(unsigned)f2bf(a) | ((int)(unsigned)f2bf(b) << 16);
#endif
}

// pair-packed activation for 4 cells (cols r=0..3 of one (j,mt), unit u):
// gates C0..C3 (f4v), state SV (f4v reg lvalue), writes 4 bf16 col-scattered
// at HW + {0,256,512,768}.
#define ACTW(C0, C1, C2, C3, SV, HW)                                           \
    {                                                                          \
        int pka_[2];                                                           \
        _Pragma("unroll") for (int p = 0; p < 2; ++p) {                        \
            f2v ei_, ef_, eg_, eo_;                                            \
            ei_[0] = __builtin_amdgcn_exp2f(C0[2*p]);                          \
            ei_[1] = __builtin_amdgcn_exp2f(C0[2*p+1]);                        \
            ef_[0] = __builtin_amdgcn_exp2f(C1[2*p]);                          \
            ef_[1] = __builtin_amdgcn_exp2f(C1[2*p+1]);                        \
            eg_[0] = __builtin_amdgcn_exp2f(C2[2*p]);                          \
            eg_[1] = __builtin_amdgcn_exp2f(C2[2*p+1]);                        \
            eo_[0] = __builtin_amdgcn_exp2f(C3[2*p]);                          \
            eo_[1] = __builtin_amdgcn_exp2f(C3[2*p+1]);                        \
            const f2v di_  = ei_ + 1.0f;                                       \
            const f2v df_  = ef_ + 1.0f;                                       \
            const f2v dg_  = eg_ + 1.0f;                                       \
            const f2v dob_ = eo_ + 1.0f;                                       \
            const f2v tig_ = di_ * dg_;                                        \
            const f2v t3_  = (dg_ * (2.0f * L2E) - (4.0f * L2E)) * df_;        \
            f2v sc_; sc_[0] = SV[2*p]; sc_[1] = SV[2*p+1];                     \
            const f2v num_ = sc_ * tig_ + t3_;                                 \
            const f2v den_ = tig_ * df_;                                       \
            f2v rd_;                                                           \
            rd_[0] = __builtin_amdgcn_rcpf(den_[0]);                           \
            rd_[1] = __builtin_amdgcn_rcpf(den_[1]);                           \
            const f2v sp_ = num_ * rd_;                                        \
            SV[2*p] = sp_[0]; SV[2*p+1] = sp_[1];                              \
            f2v ec_;                                                           \
            ec_[0] = __builtin_amdgcn_exp2f(sp_[0]);                           \
            ec_[1] = __builtin_amdgcn_exp2f(sp_[1]);                           \
            const f2v dcc_ = ec_ + 1.0f;                                       \
            const f2v hd_  = dob_ * dcc_;                                      \
            f2v rh_;                                                           \
            rh_[0] = __builtin_amdgcn_rcpf(hd_[0]);                            \
            rh_[1] = __builtin_amdgcn_rcpf(hd_[1]);                            \
            const f2v hv_ = (2.0f - dcc_) * rh_;                               \
            pka_[p] = pk_bf16(hv_[0], hv_[1]);                                 \
        }                                                                      \
        *(short*)((HW) + 0)   = (short)pka_[0];                                \
        *(short*)((HW) + 256) = (short)(pka_[0] >> 16);                        \
        *(short*)((HW) + 512) = (short)pka_[1];                                \
        *(short*)((HW) + 768) = (short)(pka_[1] >> 16);                        \
    }

__global__ void __attribute__((amdgpu_flat_work_group_size(256, 256)))
               __attribute__((amdgpu_waves_per_eu(1, 1)))
lstm_mfma_kernel(const float* __restrict__ x,
                 const float* __restrict__ W_ih,
                 const float* __restrict__ W_hh,
                 const float* __restrict__ b_ih,
                 const float* __restrict__ b_hh,
                 const float* __restrict__ fc_W,
                 const float* __restrict__ fc_b,
                 float* __restrict__ out)
{
    const int pb = blockIdx.x;        // window octet 0..29
    const int g  = blockIdx.y;        // batch group 0..7
    const int j  = threadIdx.x;       // 0..255
    const int wv = j >> 6;            // wave 0..3, owns windows w0+2wv..+1
    const int l  = j & 63;
    const int lm = l & 15;
    const int lq = l >> 4;

    const int w0 = 8 * pb;
    const int base_b = 16 * g;

    // LDS: [0, 98304) W^T B-frags kt=0..2: frag (T,kt) at (T*3+kt)*1024 B,
    //      lane l's 16 B at +l*16.  [98304, 131072): per-wave h-buf,
    //      h[col][u] bf16, col stride 256 B (col 0..31, u 0..127).
    __shared__ __attribute__((aligned(16))) short lds_s[65536];   // 128 KiB
    short* const Wl = lds_s;
    char*  const hB = (char*)lds_s + 98304 + wv * 8192;

    // ---- stage W^T kt=0..2 into LDS (Kc folded): lane l of frag (T,kt)
    //      holds B[k=kt*32+lq*8+e][n=T*16+lm] = Kc * W_hh[T*16+lm][k] ----
    for (int T = wv; T < 32; T += 4) {
        const float Kc = ((T >> 3) == 2) ? (-2.0f * L2E) : (-L2E);
#pragma unroll
        for (int kt = 0; kt < 3; ++kt) {
            const float* src = W_hh + (T * 16 + lm) * 128 + kt * 32 + lq * 8;
            float4 v0 = ((const float4*)src)[0];
            float4 v1 = ((const float4*)src)[1];
            s8v tv;
            tv[0]=(short)f2bf(Kc*v0.x); tv[1]=(short)f2bf(Kc*v0.y);
            tv[2]=(short)f2bf(Kc*v0.z); tv[3]=(short)f2bf(Kc*v0.w);
            tv[4]=(short)f2bf(Kc*v1.x); tv[5]=(short)f2bf(Kc*v1.y);
            tv[6]=(short)f2bf(Kc*v1.z); tv[7]=(short)f2bf(Kc*v1.w);
            *(s8v*)(Wl + (T * 3 + kt) * 512 + l * 8) = tv;
        }
    }

    // ---- kt=3 B-frags resident (wf3[gate][j], 128 VGPRs) ----
    bf8 wf3[4][8];
#pragma unroll
    for (int gt = 0; gt < 4; ++gt) {
        const float Kc = (gt == 2) ? (-2.0f * L2E) : (-L2E);
#pragma unroll
        for (int jj = 0; jj < 8; ++jj) {
            const float* src = W_hh + ((8 * gt + jj) * 16 + lm) * 128 + 96 + lq * 8;
            float4 v0 = ((const float4*)src)[0];
            float4 v1 = ((const float4*)src)[1];
            s8v tv;
            tv[0]=(short)f2bf(Kc*v0.x); tv[1]=(short)f2bf(Kc*v0.y);
            tv[2]=(short)f2bf(Kc*v0.z); tv[3]=(short)f2bf(Kc*v0.w);
            tv[4]=(short)f2bf(Kc*v1.x); tv[5]=(short)f2bf(Kc*v1.y);
            tv[6]=(short)f2bf(Kc*v1.z); tv[7]=(short)f2bf(Kc*v1.w);
            wf3[gt][jj] = __builtin_bit_cast(bf8, tv);
        }
    }

    // ---- wih/bias resident: unit u = 16*jj + lm, row = gt*128 + u ----
    float wihK[4][8], biasK[4][8];
#pragma unroll
    for (int gt = 0; gt < 4; ++gt) {
        const float Kc = (gt == 2) ? (-2.0f * L2E) : (-L2E);
#pragma unroll
        for (int jj = 0; jj < 8; ++jj) {
            const int row = gt * 128 + 16 * jj + lm;
            wihK[gt][jj]  = Kc * W_ih[row];
            biasK[gt][jj] = Kc * (b_ih[row] + b_hh[row]);
        }
    }

    // ---- zero own h-buf (h(0) = 0); wave-local, no barrier needed ----
    for (int i = l; i < 512; i += 64)
        ((int4*)hB)[i] = make_int4(0, 0, 0, 0);

    if (pb == 0) {                    // out[:, :16] = x[:, :16]
        const int n = j >> 4, tt = j & 15;
        out[(base_b + n) * TT + tt] = x[(base_b + n) * TT + tt];
    }

    // x: lane's col (mt,r) = batch 4*lq+r, window w0+2*wv+mt, element +t
    const float* xp = x + (base_b + 4 * lq) * TT + w0 + 2 * wv;

    f4v cst[8][2] = {};               // [j][mt], components r; s = -2*L2E*c
    // h-write base: col = 16*mt + 4*lq (+r), byte = col*256 + u*2
    char* const hwb = hB + (4 * lq) * 256 + lm * 2;

    __syncthreads();                  // W staged (the ONLY block barrier)

    f4v x4[2];                        // x for step t, [mt], components r
#pragma unroll
    for (int mt = 0; mt < 2; ++mt)
#pragma unroll
        for (int r = 0; r < 4; ++r)
            x4[mt][r] = xp[r * TT + mt];

    for (int t = 0; t < 16; ++t) {
        // prefetch x(t+1) (t=15 reads unused in-bounds values)
        f4v x4n[2];
#pragma unroll
        for (int mt = 0; mt < 2; ++mt)
#pragma unroll
            for (int r = 0; r < 4; ++r)
                x4n[mt][r] = xp[r * TT + mt + t + 1];

        // A-frags = h(t): lane A[m=lm][k=kt*32+lq*8+e] from h-buf col 16mt+lm
        bf8 af[2][4];
#pragma unroll
        for (int mt = 0; mt < 2; ++mt)
#pragma unroll
            for (int kt = 0; kt < 4; ++kt)
                af[mt][kt] = *(const bf8*)(hB + (16 * mt + lm) * 256 +
                                           kt * 64 + lq * 16);

#pragma unroll
        for (int jj = 0; jj < 8; ++jj) {
            bf8 wf[4][3];
#pragma unroll
            for (int gt = 0; gt < 4; ++gt)
#pragma unroll
                for (int kt = 0; kt < 3; ++kt)
                    wf[gt][kt] = *(const bf8*)(Wl + ((8 * gt + jj) * 3 + kt) * 512
                                               + l * 8);
            f4v c[4][2];
#pragma unroll
            for (int gt = 0; gt < 4; ++gt)
#pragma unroll
                for (int mt = 0; mt < 2; ++mt)
                    c[gt][mt] = x4[mt] * wihK[gt][jj] + biasK[gt][jj];
#pragma unroll
            for (int kt = 0; kt < 3; ++kt)
#pragma unroll
                for (int gt = 0; gt < 4; ++gt)
#pragma unroll
                    for (int mt = 0; mt < 2; ++mt)
                        c[gt][mt] = __builtin_amdgcn_mfma_f32_16x16x32_bf16(
                                        af[mt][kt], wf[gt][kt], c[gt][mt], 0, 0, 0);
#pragma unroll
            for (int gt = 0; gt < 4; ++gt)
#pragma unroll
                for (int mt = 0; mt < 2; ++mt)
                    c[gt][mt] = __builtin_amdgcn_mfma_f32_16x16x32_bf16(
                                    af[mt][3], wf3[gt][jj], c[gt][mt], 0, 0, 0);
            // ACT + h(t+1) write: unit u = 16*jj+lm, cols 16mt+4lq+r
#pragma unroll
            for (int mt = 0; mt < 2; ++mt) {
                ACTW(c[0][mt], c[1][mt], c[2][mt], c[3][mt], cst[jj][mt],
                     hwb + mt * 4096 + jj * 32)
            }
        }
        x4[0] = x4n[0];
        x4[1] = x4n[1];
    }

    // ---- epilogue (wave-local, no barrier): 2 lanes per col ----
    {
        const int c2 = l >> 1;        // col 0..31
        const int hf = l & 1;         // half of units
        const char* hc = hB + c2 * 256 + hf * 128;
        float acc = 0.f;
#pragma unroll
        for (int i = 0; i < 8; ++i) {
            const s8v hv = *(const s8v*)(hc + i * 16);
#pragma unroll
            for (int e = 0; e < 8; ++e)
                acc = fmaf(fc_W[hf * 64 + i * 8 + e], bf2f(hv[e]), acc);
        }
        acc += __shfl_xor(acc, 1);
        if (!hf) {
            float v = acc + fc_b[0];
            v = (v >= 0.f) ? v : 0.3f * v;
            out[(base_b + (c2 & 15)) * TT + WIN + w0 + 2 * wv + (c2 >> 4)] = v;
        }
    }
}

extern "C" void kernel_launch(void* const* d_in, const int* in_sizes, int n_in,
                              void* d_out, int out_size, void* d_ws, size_t ws_size,
                              hipStream_t stream) {
    const float* x    = (const float*)d_in[0];
    const float* W_ih = (const float*)d_in[1];
    const float* W_hh = (const float*)d_in[2];
    const float* b_ih = (const float*)d_in[3];
    const float* b_hh = (const float*)d_in[4];
    const float* fc_W = (const float*)d_in[5];
    const float* fc_b = (const float*)d_in[6];
    float* out = (float*)d_out;

    lstm_mfma_kernel<<<dim3(30, 8), dim3(256), 0, stream>>>(
        x, W_ih, W_hh, b_ih, b_hh, fc_W, fc_b, out);
}

// Round 14
// 210.532 us; speedup vs baseline: 1.2679x; 1.2679x over previous
//
#include <hip/hip_runtime.h>

// LSTM sliding-window scan. Round-28: PRODUCER/CONSUMER WAVE SPECIALIZATION.
// Lessons: (i) barrier-locked waves' MFMA/VALU/trans pipes are ADDITIVE
// (r5-r8, every scheduling lever null); (ii) cross-block co-residency always
// spills (r9-r12); (iii) 1 wave/SIMD can't self-hide latency (r13). This
// design satisfies all three: ONE 8-wave block per CU, waves 0-3 = GEMM
// (wave w = gate w: rows [128w,128w+128), afr[8][4]=128 VGPR, pure MFMA),
// waves 4-7 = ACT (all trans + cell state in regs). Round-robin wave->SIMD
// puts 1 GEMM + 1 ACT wave per SIMD -> matrix pipe and trans/VALU pipe fed
// SIMULTANEOUSLY by different waves (m114), no lockstep. Gates move through
// a double-buffered f32 LDS buffer gbuf[2][gate][u][col16] at nt-slot
// granularity, lag-1 pipeline: slot k GEMM writes gates(k) || ACT consumes
// gates(k-1); one barrier per slot (8/step; both role-loops execute equal
// barrier counts). Slot order: (q0,nt0..3),(q1,nt0..3); gbuf parity = k&1
// (static); h double-buffered per quad (r6 layout, B-frag-ready); hazard
// check: every region has >=1 barrier producer->consumer; h WAR safe via
// parity. Roles branch-separated top-level so live ranges don't sum
// (GEMM ~200 regs, ACT ~130). LDS 144 KiB; grid 30x8=240, 1 block/CU.
// Numerics = r6 path exactly (f32 gates/wih/bias, bf16 W_hh/h):
//   s' = [s*di*dg + (2log2e*dg - 4log2e)*df] * rcp(di*dg*df)
//   h  = (2-dcc) * rcp(dob*dcc), dcc = 1+exp2(s')  (5 exp2 + 2 rcp / cell)
// Gate scale -log2e (-2log2e for g) folded into weights/biases.

#define TT   256
#define WIN  16
#define L2E  1.4426950408889634f

typedef __bf16 bf8 __attribute__((ext_vector_type(8)));
typedef short  s8v __attribute__((ext_vector_type(8)));
typedef float  f4v __attribute__((ext_vector_type(4)));
typedef float  f2v __attribute__((ext_vector_type(2)));
typedef int    i2v __attribute__((ext_vector_type(2)));

__device__ __forceinline__ unsigned short f2bf(float f) {
    unsigned u = __builtin_bit_cast(unsigned, f);
    return (unsigned short)((u + 0x8000u) >> 16);   // round-half-up to bf16
}
__device__ __forceinline__ float bf2f(short h) {
    return __builtin_bit_cast(float, ((unsigned)(unsigned short)h) << 16);
}
__device__ __forceinline__ int pk_bf16(float a, float b) {
#if __has_builtin(__builtin_amdgcn_cvt_pk_bf16_f32)
    return __builtin_bit_cast(int, __builtin_amdgcn_cvt_pk_bf16_f32(a, b));
#else
    return (int)(unsigned)f2bf(a) | ((int)(unsigned)f2bf(b) << 16);
#endif
}

// pair-packed activation for 4 cells: gates C0..C3 (f4v), state SV (f4v reg
// lvalue, pre-scaled s = -2*L2E*c), writes 4 bf16 (i2v) to HWA.
#define ACT4(C0, C1, C2, C3, SV, HWA)                                          \
    {                                                                          \
        i2v pk_;                                                               \
        _Pragma("unroll") for (int p_ = 0; p_ < 2; ++p_) {                     \
            f2v ei_, ef_, eg_, eo_;                                            \
            ei_[0] = __builtin_amdgcn_exp2f(C0[2*p_]);                         \
            ei_[1] = __builtin_amdgcn_exp2f(C0[2*p_+1]);                       \
            ef_[0] = __builtin_amdgcn_exp2f(C1[2*p_]);                         \
            ef_[1] = __builtin_amdgcn_exp2f(C1[2*p_+1]);                       \
            eg_[0] = __builtin_amdgcn_exp2f(C2[2*p_]);                         \
            eg_[1] = __builtin_amdgcn_exp2f(C2[2*p_+1]);                       \
            eo_[0] = __builtin_amdgcn_exp2f(C3[2*p_]);                         \
            eo_[1] = __builtin_amdgcn_exp2f(C3[2*p_+1]);                       \
            const f2v di_  = ei_ + 1.0f;                                       \
            const f2v df_  = ef_ + 1.0f;                                       \
            const f2v dg_  = eg_ + 1.0f;                                       \
            const f2v dob_ = eo_ + 1.0f;                                       \
            const f2v tig_ = di_ * dg_;                                        \
            const f2v t3_  = (dg_ * (2.0f * L2E) - (4.0f * L2E)) * df_;        \
            f2v sc_; sc_[0] = SV[2*p_]; sc_[1] = SV[2*p_+1];                   \
            const f2v num_ = sc_ * tig_ + t3_;                                 \
            const f2v den_ = tig_ * df_;                                       \
            f2v rd_;                                                           \
            rd_[0] = __builtin_amdgcn_rcpf(den_[0]);                           \
            rd_[1] = __builtin_amdgcn_rcpf(den_[1]);                           \
            const f2v sp_ = num_ * rd_;                                        \
            SV[2*p_] = sp_[0]; SV[2*p_+1] = sp_[1];                            \
            f2v ec_;                                                           \
            ec_[0] = __builtin_amdgcn_exp2f(sp_[0]);                           \
            ec_[1] = __builtin_amdgcn_exp2f(sp_[1]);                           \
            const f2v dcc_ = ec_ + 1.0f;                                       \
            const f2v hd_  = dob_ * dcc_;                                      \
            f2v rh_;                                                           \
            rh_[0] = __builtin_amdgcn_rcpf(hd_[0]);                            \
            rh_[1] = __builtin_amdgcn_rcpf(hd_[1]);                            \
            const f2v hv_ = (2.0f - dcc_) * rh_;                               \
            pk_[p_] = pk_bf16(hv_[0], hv_[1]);                                 \
        }                                                                      \
        *(i2v*)(HWA) = pk_;                                                    \
    }

// GEMM slot: quad Q, col-group NT, gates parity PAR. Wave w (= gate) computes
// gates rows [128w,128w+128) x cols [16NT,16NT+16) of quad Q and writes f32
// to gbuf[PAR][w][u][col].  (p = h-read parity, ss = step, set in loop.)
#define GSLOT(Q, NT, PAR)                                                      \
    {                                                                          \
        const short* hb_ = &Hbuf[Q][p][0];                                     \
        const bf8 b0_ = *(const bf8*)(hb_ + (NT)*2048 + 0*512 + l*8);          \
        const bf8 b1_ = *(const bf8*)(hb_ + (NT)*2048 + 1*512 + l*8);          \
        const bf8 b2_ = *(const bf8*)(hb_ + (NT)*2048 + 2*512 + l*8);          \
        const bf8 b3_ = *(const bf8*)(hb_ + (NT)*2048 + 3*512 + l*8);          \
        const float xv_ = xst[Q][ss*64 + (NT)*16 + lm];                        \
        float* gw_ = gbufF + (PAR)*8192 + w*2048 + (4*lq)*16 + lm;             \
        _Pragma("unroll") for (int mi = 0; mi < 8; ++mi) {                     \
            const int r0_ = 128*w + 16*mi + 4*lq;                              \
            f4v c_ = (*(const f4v*)(wbL + r0_)) * xv_ +                        \
                     (*(const f4v*)(wbL + 512 + r0_));                         \
            c_ = __builtin_amdgcn_mfma_f32_16x16x32_bf16(afr[mi][0], b0_, c_, 0,0,0); \
            c_ = __builtin_amdgcn_mfma_f32_16x16x32_bf16(afr[mi][1], b1_, c_, 0,0,0); \
            c_ = __builtin_amdgcn_mfma_f32_16x16x32_bf16(afr[mi][2], b2_, c_, 0,0,0); \
            c_ = __builtin_amdgcn_mfma_f32_16x16x32_bf16(afr[mi][3], b3_, c_, 0,0,0); \
            gw_[(16*mi+0)*16] = c_[0];                                         \
            gw_[(16*mi+1)*16] = c_[1];                                         \
            gw_[(16*mi+2)*16] = c_[2];                                         \
            gw_[(16*mi+3)*16] = c_[3];                                         \
        }                                                                      \
    }

// ACT slot: consume gates(Q,NT) from gbuf[PAR], update cst[Q][NT], write
// h(t+1) bf16 into Hbuf[Q][BUFI]. Lane: col cl = l&15, units u0a..u0a+7.
#define ASLOT(Q, NT, PAR, BUFI)                                                \
    {                                                                          \
        const float* gb_ = gbufF + (PAR)*8192;                                 \
        short* hw_ = &Hbuf[Q][BUFI][0] + (NT)*2048 + hwoff;                    \
        _Pragma("unroll") for (int hh = 0; hh < 2; ++hh) {                     \
            f4v C0_, C1_, C2_, C3_;                                            \
            _Pragma("unroll") for (int r_ = 0; r_ < 4; ++r_) {                 \
                const int ui_ = (u0a + 4*hh + r_) * 16 + cl;                   \
                C0_[r_] = gb_[ui_];                                            \
                C1_[r_] = gb_[2048 + ui_];                                     \
                C2_[r_] = gb_[4096 + ui_];                                     \
                C3_[r_] = gb_[6144 + ui_];                                     \
            }                                                                  \
            ACT4(C0_, C1_, C2_, C3_, cst[Q][NT][hh], hw_ + 4*hh)               \
        }                                                                      \
    }

__global__ void __attribute__((amdgpu_flat_work_group_size(512, 512)))
               __attribute__((amdgpu_waves_per_eu(2)))
lstm_mfma_kernel(const float* __restrict__ x,
                 const float* __restrict__ W_ih,
                 const float* __restrict__ W_hh,
                 const float* __restrict__ b_ih,
                 const float* __restrict__ b_hh,
                 const float* __restrict__ fc_W,
                 const float* __restrict__ fc_b,
                 float* __restrict__ out)
{
    const int pb = blockIdx.x;        // window octet 0..29
    const int g  = blockIdx.y;        // batch group 0..7
    const int j  = threadIdx.x;       // 0..511
    const int w  = j >> 6;            // wave 0..7 (0-3 GEMM, 4-7 ACT)
    const int l  = j & 63;
    const int lm = l & 15;
    const int lq = l >> 4;

    const int w0 = 8 * pb;            // windows w0..w0+7 (2 quads)
    const int base_b = 16 * g;

    // H layout (r6, B-frag-ready): [quad][buf][nt*2048 + kt*512 + lq*128 + n*8 + jj]
    __shared__ short Hbuf[2][2][8192];     // 64 KiB
    __shared__ float gbuf[2][4][128][16];  // 64 KiB  [par][gate][u][col]
    __shared__ float xst[2][1024];         // 8 KiB   [quad][step*64+col]
    __shared__ float wbL[1024];            // 4 KiB   [0:512) Kc*wih, [512:) Kc*bias
    __shared__ float parts[2][512];        // 4 KiB   (total 147456 B)
    float* const gbufF = &gbuf[0][0][0][0];

    // ---- staging (all waves) ----
    {   // wih/bias, Kc-scaled f32
        const float Kc = ((j >> 7) == 2) ? (-2.0f * L2E) : (-L2E);
        wbL[j]       = Kc * W_ih[j];
        wbL[512 + j] = Kc * (b_ih[j] + b_hh[j]);
    }
    for (int i = j; i < 2048; i += 512) {  // x: col c=nt*16+n runs window
        const int q = i >> 10, idx = i & 1023;   // w0+4q+nt of batch base_b+n
        const int t = idx >> 6, c = idx & 63;
        const int nt = c >> 4, n = c & 15;
        xst[q][idx] = x[(base_b + n) * TT + (w0 + 4 * q + nt) + t];
    }
    for (int i = j; i < 1024; i += 512) {  // h(0) = 0 both quads
        ((int4*)&Hbuf[0][0][0])[i] = make_int4(0, 0, 0, 0);
        ((int4*)&Hbuf[1][0][0])[i] = make_int4(0, 0, 0, 0);
    }
    if (pb == 0 && j < 256) {              // out[:, :16] = x[:, :16]
        const int n = j >> 4, tt = j & 15;
        out[(base_b + n) * TT + tt] = x[(base_b + n) * TT + tt];
    }

    // ---- GEMM waves: A-fragments for gate w, rows 128w+16mi+lm ----
    bf8 afr[8][4];                    // 128 VGPR (GEMM path only)
    if (w < 4) {
        const float Kc = (w == 2) ? (-2.0f * L2E) : (-L2E);
#pragma unroll
        for (int mi = 0; mi < 8; ++mi) {
            const int row = 128 * w + 16 * mi + lm;
#pragma unroll
            for (int kt = 0; kt < 4; ++kt) {
                const float* src = W_hh + row * 128 + kt * 32 + lq * 8;
                float4 v0 = ((const float4*)src)[0];
                float4 v1 = ((const float4*)src)[1];
                s8v tv;
                tv[0]=(short)f2bf(Kc*v0.x); tv[1]=(short)f2bf(Kc*v0.y);
                tv[2]=(short)f2bf(Kc*v0.z); tv[3]=(short)f2bf(Kc*v0.w);
                tv[4]=(short)f2bf(Kc*v1.x); tv[5]=(short)f2bf(Kc*v1.y);
                tv[6]=(short)f2bf(Kc*v1.z); tv[7]=(short)f2bf(Kc*v1.w);
                afr[mi][kt] = __builtin_bit_cast(bf8, tv);
            }
        }
    }
    __syncthreads();

    if (w < 4) {
        // ================= GEMM role =================
        for (int ss = 0; ss < 16; ++ss) {
            const int p = ss & 1;     // h(ss) buffer
            GSLOT(0, 0, 0) __syncthreads();
            GSLOT(0, 1, 1) __syncthreads();
            GSLOT(0, 2, 0) __syncthreads();
            GSLOT(0, 3, 1) __syncthreads();
            GSLOT(1, 0, 0) __syncthreads();
            GSLOT(1, 1, 1) __syncthreads();
            GSLOT(1, 2, 0) __syncthreads();
            GSLOT(1, 3, 1) __syncthreads();
        }
        __syncthreads();              // match ACT tail barrier
    } else {
        // ================= ACT role =================
        f4v cst[2][4][2] = {};        // [quad][nt][half], s = -2*L2E*c
        const int a   = w - 4;
        const int cl  = l & 15;
        const int u0a = (l >> 4) * 32 + a * 8;     // u0a % 8 == 0
        const int hwoff = (u0a >> 5) * 512 + ((u0a >> 3) & 3) * 128 + cl * 8;
        for (int ss = 0; ss < 16; ++ss) {
            const int p = ss & 1, q = p ^ 1;
            if (ss) ASLOT(1, 3, 1, p)           // finish h(ss) (t'=ss-1)
            __syncthreads();
            ASLOT(0, 0, 0, q) __syncthreads();  // t'=ss -> h(ss+1)
            ASLOT(0, 1, 1, q) __syncthreads();
            ASLOT(0, 2, 0, q) __syncthreads();
            ASLOT(0, 3, 1, q) __syncthreads();
            ASLOT(1, 0, 0, q) __syncthreads();
            ASLOT(1, 1, 1, q) __syncthreads();
            ASLOT(1, 2, 0, q) __syncthreads();
        }
        ASLOT(1, 3, 1, 0)             // t'=15 -> h(16) into buf 0
        __syncthreads();
    }

    // ---- epilogue: h(16) in Hbuf[q][0]; col c -> out[...,16+w0+4q+(c>>4)] ----
    {
        const int c  = j >> 3;        // 0..63
        const int pp = j & 7;         // unit chunk: units pp*16 .. pp*16+15
        const int nt = c >> 4, n = c & 15;
#pragma unroll
        for (int q = 0; q < 2; ++q) {
            const short* hf = &Hbuf[q][0][0] + nt * 2048;
            float acc = 0.f;
#pragma unroll
            for (int h8 = 0; h8 < 2; ++h8) {
                const int ub = pp * 16 + 8 * h8;       // ub&7 == 0
                const s8v hv = *(const s8v*)(hf + (ub >> 5) * 512 +
                                             ((ub >> 3) & 3) * 128 + n * 8);
#pragma unroll
                for (int ii = 0; ii < 8; ++ii)
                    acc = fmaf(fc_W[ub + ii], bf2f(hv[ii]), acc);
            }
            parts[q][j] = acc;
        }
    }
    __syncthreads();
    if (j < 128) {
        const int q = j >> 6, c = j & 63;
        float v = fc_b[0];
#pragma unroll
        for (int k = 0; k < 8; ++k) v += parts[q][c * 8 + k];
        const int nt = c >> 4, n = c & 15;
        out[(base_b + n) * TT + WIN + w0 + 4 * q + nt] = (v >= 0.f) ? v : 0.3f * v;
    }
}

extern "C" void kernel_launch(void* const* d_in, const int* in_sizes, int n_in,
                              void* d_out, int out_size, void* d_ws, size_t ws_size,
                              hipStream_t stream) {
    const float* x    = (const float*)d_in[0];
    const float* W_ih = (const float*)d_in[1];
    const float* W_hh = (const float*)d_in[2];
    const float* b_ih = (const float*)d_in[3];
    const float* b_hh = (const float*)d_in[4];
    const float* fc_W = (const float*)d_in[5];
    const float* fc_b = (const float*)d_in[6];
    float* out = (float*)d_out;

    lstm_mfma_kernel<<<dim3(30, 8), dim3(512), 0, stream>>>(
        x, W_ih, W_hh, b_ih, b_hh, fc_W, fc_b, out);
}